// Round 2
// baseline (616.325 us; speedup 1.0000x reference)
//
#include <hip/hip_runtime.h>
#include <math.h>

#define NTOT  16384
#define NNODE 1024

// ---------------- embedding: h = obs @ Wemb + b (K=32, N=128) ----------------
__global__ __launch_bounds__(64) void emb_k(const float* __restrict__ obs,
    const float* __restrict__ W, const float* __restrict__ b,
    float* __restrict__ h, float* __restrict__ hh)
{
  int n = blockIdx.x, l = threadIdx.x;
  __shared__ float ob[32];
  if (l < 32) ob[l] = obs[n * 32 + l];
  __syncthreads();
  float a0 = b[l], a1 = b[64 + l];
  #pragma unroll
  for (int k = 0; k < 32; ++k) {
    float o = ob[k];
    a0 = fmaf(o, W[k * 128 + l], a0);
    a1 = fmaf(o, W[k * 128 + 64 + l], a1);
  }
  size_t base = (size_t)n * 128;
  h[base + l] = a0;  h[base + 64 + l] = a1;
  hh[base + l] = a0; hh[base + 64 + l] = a1;
}

// ---------------- CSR build ----------------
__global__ void hist_k(const int* __restrict__ ei, int E0, int* __restrict__ deg)
{
  int i = blockIdx.x * blockDim.x + threadIdx.x;
  int ET = E0 + NTOT;
  if (i < ET) {
    int d = (i < E0) ? ei[E0 + i] : (i - E0);
    atomicAdd(&deg[d], 1);
  }
}

__global__ __launch_bounds__(256) void scan_k(const int* __restrict__ deg,
    int* __restrict__ off, int* __restrict__ cursor)
{
  __shared__ int part[256];
  int t = threadIdx.x;
  int base = t * 64;
  int sum = 0;
  for (int i = 0; i < 64; ++i) sum += deg[base + i];
  part[t] = sum;
  __syncthreads();
  if (t == 0) {
    int run = 0;
    for (int i = 0; i < 256; ++i) { int v = part[i]; part[i] = run; run += v; }
  }
  __syncthreads();
  int run = part[t];
  for (int i = 0; i < 64; ++i) {
    off[base + i] = run; cursor[base + i] = run;
    run += deg[base + i];
  }
  if (t == 255) off[NTOT] = run;
}

__global__ void scat_k(const int* __restrict__ ei, int E0,
    int* __restrict__ cursor, int* __restrict__ csr_src)
{
  int i = blockIdx.x * blockDim.x + threadIdx.x;
  int ET = E0 + NTOT;
  if (i < ET) {
    int s, d;
    if (i < E0) { s = ei[i]; d = ei[E0 + i]; } else { s = d = i - E0; }
    int pos = atomicAdd(&cursor[d], 1);
    csr_src[pos] = s;
  }
}

// static fully-connected 16-node cluster graphs (self-loops once)
__global__ void hi_k(int* __restrict__ hi_off, int* __restrict__ hi_src)
{
  int t = threadIdx.x;
  hi_off[t] = t * 16;
  if (t == 0) hi_off[256] = 4096;
  for (int i = t; i < 4096; i += 256) {
    int u = i >> 4;                 // dst node 0..255
    hi_src[i] = (u & ~15) + (i & 15);
  }
}

// ---------------- fp32 tiled GEMM: C = A[M,K] @ W[K,N] + bias, opt tanh / +res
__global__ __launch_bounds__(256) void gemm_f32(
    const float* __restrict__ A, const float* __restrict__ W,
    const float* __restrict__ bias, float* __restrict__ C,
    int M, int K, int N, int act, const float* __restrict__ res)
{
  __shared__ float Ast[16][68];   // [k][m], padded
  __shared__ float Bs[16][68];    // [k][n], padded
  const int tid = threadIdx.x;
  const int bm = blockIdx.x * 64, bn = blockIdx.y * 64;
  const int ty = tid >> 4, tx = tid & 15;
  const int tr = ty * 4, tc = tx * 4;
  const int ar = tid >> 2, ak = (tid & 3) << 2;
  const int bk = tid >> 4, bnn = (tid & 15) << 2;
  float acc[4][4] = {};
  for (int k0 = 0; k0 < K; k0 += 16) {
    float4 av = *(const float4*)(A + (size_t)(bm + ar) * K + k0 + ak);
    float4 bv = *(const float4*)(W + (size_t)(k0 + bk) * N + bn + bnn);
    Ast[ak + 0][ar] = av.x; Ast[ak + 1][ar] = av.y;
    Ast[ak + 2][ar] = av.z; Ast[ak + 3][ar] = av.w;
    *(float4*)&Bs[bk][bnn] = bv;
    __syncthreads();
    #pragma unroll
    for (int kk = 0; kk < 16; ++kk) {
      float4 a = *(const float4*)&Ast[kk][tr];
      float4 b = *(const float4*)&Bs[kk][tc];
      acc[0][0] = fmaf(a.x, b.x, acc[0][0]); acc[0][1] = fmaf(a.x, b.y, acc[0][1]);
      acc[0][2] = fmaf(a.x, b.z, acc[0][2]); acc[0][3] = fmaf(a.x, b.w, acc[0][3]);
      acc[1][0] = fmaf(a.y, b.x, acc[1][0]); acc[1][1] = fmaf(a.y, b.y, acc[1][1]);
      acc[1][2] = fmaf(a.y, b.z, acc[1][2]); acc[1][3] = fmaf(a.y, b.w, acc[1][3]);
      acc[2][0] = fmaf(a.z, b.x, acc[2][0]); acc[2][1] = fmaf(a.z, b.y, acc[2][1]);
      acc[2][2] = fmaf(a.z, b.z, acc[2][2]); acc[2][3] = fmaf(a.z, b.w, acc[2][3]);
      acc[3][0] = fmaf(a.w, b.x, acc[3][0]); acc[3][1] = fmaf(a.w, b.y, acc[3][1]);
      acc[3][2] = fmaf(a.w, b.z, acc[3][2]); acc[3][3] = fmaf(a.w, b.w, acc[3][3]);
    }
    __syncthreads();
  }
  const float4 bb = *(const float4*)(bias + bn + tc);
  #pragma unroll
  for (int i = 0; i < 4; ++i) {
    int row = bm + tr + i;
    float4 v = make_float4(acc[i][0] + bb.x, acc[i][1] + bb.y,
                           acc[i][2] + bb.z, acc[i][3] + bb.w);
    if (act == 1) { v.x = tanhf(v.x); v.y = tanhf(v.y); v.z = tanhf(v.z); v.w = tanhf(v.w); }
    if (res) {
      const float4 rr = *(const float4*)(res + (size_t)row * N + bn + tc);
      v.x += rr.x; v.y += rr.y; v.z += rr.z; v.w += rr.w;
    }
    *(float4*)(C + (size_t)row * N + bn + tc) = v;
  }
}

// ---------------- fused GATv2 aggregate + mean-heads + bias + LN (+SiLU) + residual(s)
// one wave per dst node; lane l owns elements l*8 .. l*8+7 of the 512-wide (4x128) features
__global__ __launch_bounds__(64) void gat_agg(
    const float* __restrict__ xl, const float* __restrict__ xr,
    const int* __restrict__ off, const int* __restrict__ srcs,
    const float* __restrict__ att, const float* __restrict__ bias,
    const float* __restrict__ g, const float* __restrict__ beta,
    float* __restrict__ h, const float* __restrict__ res2, int do_silu)
{
  int dst = blockIdx.x, l = threadIdx.x;
  float xrr[8], attr[8];
  {
    const float4 x0 = *(const float4*)(xr + (size_t)dst * 512 + l * 8);
    const float4 x1 = *(const float4*)(xr + (size_t)dst * 512 + l * 8 + 4);
    xrr[0] = x0.x; xrr[1] = x0.y; xrr[2] = x0.z; xrr[3] = x0.w;
    xrr[4] = x1.x; xrr[5] = x1.y; xrr[6] = x1.z; xrr[7] = x1.w;
    const float4 a0 = *(const float4*)(att + l * 8);
    const float4 a1 = *(const float4*)(att + l * 8 + 4);
    attr[0] = a0.x; attr[1] = a0.y; attr[2] = a0.z; attr[3] = a0.w;
    attr[4] = a1.x; attr[5] = a1.y; attr[6] = a1.z; attr[7] = a1.w;
  }
  int e0 = off[dst], e1 = off[dst + 1];
  float m = -1e30f;
  for (int e = e0; e < e1; ++e) {
    const float* xlp = xl + (size_t)srcs[e] * 512 + l * 8;
    const float4 u0 = *(const float4*)xlp;
    const float4 u1 = *(const float4*)(xlp + 4);
    float xv[8] = {u0.x, u0.y, u0.z, u0.w, u1.x, u1.y, u1.z, u1.w};
    float part = 0.f;
    #pragma unroll
    for (int i = 0; i < 8; ++i) {
      float v = xv[i] + xrr[i];
      v = v > 0.f ? v : 0.2f * v;
      part = fmaf(v, attr[i], part);
    }
    part += __shfl_xor(part, 1); part += __shfl_xor(part, 2);
    part += __shfl_xor(part, 4); part += __shfl_xor(part, 8);
    m = fmaxf(m, part);
  }
  float z = 0.f, acc[8] = {0.f, 0.f, 0.f, 0.f, 0.f, 0.f, 0.f, 0.f};
  for (int e = e0; e < e1; ++e) {
    const float* xlp = xl + (size_t)srcs[e] * 512 + l * 8;
    const float4 u0 = *(const float4*)xlp;
    const float4 u1 = *(const float4*)(xlp + 4);
    float xv[8] = {u0.x, u0.y, u0.z, u0.w, u1.x, u1.y, u1.z, u1.w};
    float part = 0.f;
    #pragma unroll
    for (int i = 0; i < 8; ++i) {
      float v = xv[i] + xrr[i];
      v = v > 0.f ? v : 0.2f * v;
      part = fmaf(v, attr[i], part);
    }
    part += __shfl_xor(part, 1); part += __shfl_xor(part, 2);
    part += __shfl_xor(part, 4); part += __shfl_xor(part, 8);
    float p = expf(part - m);
    z += p;
    #pragma unroll
    for (int i = 0; i < 8; ++i) acc[i] = fmaf(p, xv[i], acc[i]);
  }
  float inv = 0.25f / z;          // mean over 4 heads folded in
  int d0 = (l & 15) * 8;
  float o[8];
  #pragma unroll
  for (int i = 0; i < 8; ++i) {
    float v = acc[i] * inv;
    v += __shfl_xor(v, 16);       // sum the 4 heads
    v += __shfl_xor(v, 32);
    o[i] = v + bias[d0 + i];
  }
  // LayerNorm over the 128 dims (each 16-lane group holds a full copy)
  float ssum = 0.f;
  #pragma unroll
  for (int i = 0; i < 8; ++i) ssum += o[i];
  ssum += __shfl_xor(ssum, 1); ssum += __shfl_xor(ssum, 2);
  ssum += __shfl_xor(ssum, 4); ssum += __shfl_xor(ssum, 8);
  float mu = ssum * (1.f / 128.f);
  float vs = 0.f;
  #pragma unroll
  for (int i = 0; i < 8; ++i) { float d = o[i] - mu; vs += d * d; }
  vs += __shfl_xor(vs, 1); vs += __shfl_xor(vs, 2);
  vs += __shfl_xor(vs, 4); vs += __shfl_xor(vs, 8);
  float rstd = rsqrtf(vs * (1.f / 128.f) + 1e-5f);
  if (l < 16) {
    size_t base = (size_t)dst * 128 + d0;
    float out[8];
    #pragma unroll
    for (int i = 0; i < 8; ++i) {
      float y = (o[i] - mu) * rstd * g[d0 + i] + beta[d0 + i];
      if (do_silu) y = y / (1.f + expf(-y));
      float r = h[base + i];
      if (res2) r += res2[base + i];
      out[i] = y + r;
    }
    *(float4*)(h + base) = make_float4(out[0], out[1], out[2], out[3]);
    *(float4*)(h + base + 4) = make_float4(out[4], out[5], out[6], out[7]);
  }
}

// ---------------- pooling assignments: s = softmax(h @ Wp + bp) over 16 ----------------
__global__ __launch_bounds__(256) void pool_k(const float* __restrict__ h,
    const float* __restrict__ W, const float* __restrict__ b, float* __restrict__ s)
{
  __shared__ float hs[16 * 130];
  __shared__ float Ws[128 * 16];
  int t = threadIdx.x;
  int n0 = blockIdx.x * 16;
  #pragma unroll
  for (int i = 0; i < 8; ++i) {
    int idx = t + 256 * i;
    hs[(idx >> 7) * 130 + (idx & 127)] = h[(size_t)n0 * 128 + idx];
    Ws[idx] = W[idx];
  }
  __syncthreads();
  int nl = t >> 4, c = t & 15;
  float acc = b[c];
  for (int k = 0; k < 128; ++k) acc = fmaf(hs[nl * 130 + k], Ws[k * 16 + c], acc);
  float mx = acc;
  mx = fmaxf(mx, __shfl_xor(mx, 1)); mx = fmaxf(mx, __shfl_xor(mx, 2));
  mx = fmaxf(mx, __shfl_xor(mx, 4)); mx = fmaxf(mx, __shfl_xor(mx, 8));
  float p = expf(acc - mx), sum = p;
  sum += __shfl_xor(sum, 1); sum += __shfl_xor(sum, 2);
  sum += __shfl_xor(sum, 4); sum += __shfl_xor(sum, 8);
  s[(size_t)(n0 + nl) * 16 + c] = p / sum;
}

// ---------------- cluster features: Hf[b,c,:] = sum_n s[b,n,c] h[b,n,:] / max(sum_n s, 1e-5)
__global__ __launch_bounds__(128) void hf_k(const float* __restrict__ s,
    const float* __restrict__ h, float* __restrict__ Hf, float* __restrict__ HfRes)
{
  int b = blockIdx.x >> 4, c = blockIdx.x & 15, d = threadIdx.x;
  float acc = 0.f, cnt = 0.f;
  for (int n = 0; n < NNODE; ++n) {
    float sv = s[(size_t)(b * NNODE + n) * 16 + c];
    cnt += sv;
    acc = fmaf(sv, h[(size_t)(b * NNODE + n) * 128 + d], acc);
  }
  cnt = fmaxf(cnt, 1e-5f);
  float v = acc / cnt;
  Hf[(size_t)(b * 16 + c) * 128 + d] = v;
  HfRes[(size_t)(b * 16 + c) * 128 + d] = v;
}

// ---------------- unpool + residual: x = s @ Hf + hh ----------------
__global__ __launch_bounds__(64) void unpool_k(const float* __restrict__ s,
    const float* __restrict__ Hf, const float* __restrict__ hh, float* __restrict__ x)
{
  int n = blockIdx.x, l = threadIdx.x;
  int b = n >> 10;
  float a0 = 0.f, a1 = 0.f;
  #pragma unroll
  for (int c = 0; c < 16; ++c) {
    float sv = s[(size_t)n * 16 + c];
    const float* hp = Hf + (size_t)((b << 4) + c) * 128;
    a0 = fmaf(sv, hp[l], a0);
    a1 = fmaf(sv, hp[64 + l], a1);
  }
  size_t base = (size_t)n * 128;
  x[base + l] = a0 + hh[base + l];
  x[base + 64 + l] = a1 + hh[base + 64 + l];
}

extern "C" void kernel_launch(void* const* d_in, const int* in_sizes, int n_in,
                              void* d_out, int out_size, void* d_ws, size_t ws_size,
                              hipStream_t stream) {
  (void)n_in; (void)out_size; (void)ws_size;
  const float* obs    = (const float*)d_in[0];
  const int*   ei     = (const int*)d_in[1];
  const float* emb_W  = (const float*)d_in[3];
  const float* emb_b  = (const float*)d_in[4];
  const float* pool_W = (const float*)d_in[5];
  const float* pool_b = (const float*)d_in[6];
  const float* mlp_W1 = (const float*)d_in[7];
  const float* mlp_b1 = (const float*)d_in[8];
  const float* mlp_W2 = (const float*)d_in[9];
  const float* mlp_b2 = (const float*)d_in[10];
  const float* lWl = (const float*)d_in[11]; const float* lbl = (const float*)d_in[12];
  const float* lWr = (const float*)d_in[13]; const float* lbr = (const float*)d_in[14];
  const float* latt = (const float*)d_in[15]; const float* lbias = (const float*)d_in[16];
  const float* lg = (const float*)d_in[17]; const float* lbeta = (const float*)d_in[18];
  const float* hWl = (const float*)d_in[19]; const float* hbl = (const float*)d_in[20];
  const float* hWr = (const float*)d_in[21]; const float* hbr = (const float*)d_in[22];
  const float* hatt = (const float*)d_in[23]; const float* hbias = (const float*)d_in[24];
  const float* hg = (const float*)d_in[25]; const float* hbeta = (const float*)d_in[26];

  const int E0 = in_sizes[1] / 2;
  const int ET = E0 + NTOT;

  char* p = (char*)d_ws;
  auto alloc = [&](size_t bytes) -> void* {
    void* q = (void*)p;
    p += (bytes + 255) & ~(size_t)255;
    return q;
  };
  float* h     = (float*)alloc((size_t)NTOT * 128 * 4);
  float* hh    = (float*)alloc((size_t)NTOT * 128 * 4);
  float* xl    = (float*)alloc((size_t)NTOT * 512 * 4);
  float* xr    = (float*)alloc((size_t)NTOT * 512 * 4);
  float* s     = (float*)alloc((size_t)NTOT * 16 * 4);
  float* Hf    = (float*)alloc(256 * 128 * 4);
  float* HfRes = (float*)alloc(256 * 128 * 4);
  int* deg     = (int*)alloc((size_t)NTOT * 4);
  int* off     = (int*)alloc((size_t)(NTOT + 1) * 4);
  int* cursor  = (int*)alloc((size_t)NTOT * 4);
  int* csr     = (int*)alloc((size_t)ET * 4);
  int* hi_off  = (int*)alloc(257 * 4);
  int* hi_src  = (int*)alloc(4096 * 4);
  float* t     = xl;   // alias: xl is free by MLP time

  hipMemsetAsync(deg, 0, (size_t)NTOT * 4, stream);
  emb_k<<<NTOT, 64, 0, stream>>>(obs, emb_W, emb_b, h, hh);
  hist_k<<<(ET + 255) / 256, 256, 0, stream>>>(ei, E0, deg);
  scan_k<<<1, 256, 0, stream>>>(deg, off, cursor);
  scat_k<<<(ET + 255) / 256, 256, 0, stream>>>(ei, E0, cursor, csr);
  hi_k<<<1, 256, 0, stream>>>(hi_off, hi_src);

  // low-level GAT stack (in-place on h; stack residual == hh)
  for (int j = 0; j < 2; ++j) {
    gemm_f32<<<dim3(NTOT / 64, 8), 256, 0, stream>>>(h, lWl + j * 65536, lbl + j * 512,
                                                     xl, NTOT, 128, 512, 0, nullptr);
    gemm_f32<<<dim3(NTOT / 64, 8), 256, 0, stream>>>(h, lWr + j * 65536, lbr + j * 512,
                                                     xr, NTOT, 128, 512, 0, nullptr);
    gat_agg<<<NTOT, 64, 0, stream>>>(xl, xr, off, csr, latt + j * 512, lbias + j * 128,
                                     lg + j * 128, lbeta + j * 128, h,
                                     j == 1 ? hh : nullptr, j == 0 ? 1 : 0);
  }

  pool_k<<<NTOT / 16, 256, 0, stream>>>(h, pool_W, pool_b, s);
  hf_k<<<256, 128, 0, stream>>>(s, h, Hf, HfRes);

  // high-level GAT stack on 256 cluster nodes (in-place on Hf)
  for (int j = 0; j < 2; ++j) {
    gemm_f32<<<dim3(4, 8), 256, 0, stream>>>(Hf, hWl + j * 65536, hbl + j * 512,
                                             xl, 256, 128, 512, 0, nullptr);
    gemm_f32<<<dim3(4, 8), 256, 0, stream>>>(Hf, hWr + j * 65536, hbr + j * 512,
                                             xr, 256, 128, 512, 0, nullptr);
    gat_agg<<<256, 64, 0, stream>>>(xl, xr, hi_off, hi_src, hatt + j * 512, hbias + j * 128,
                                    hg + j * 128, hbeta + j * 128, Hf,
                                    j == 1 ? HfRes : nullptr, j == 0 ? 1 : 0);
  }

  float* x = (float*)d_out;
  unpool_k<<<NTOT, 64, 0, stream>>>(s, Hf, hh, x);
  gemm_f32<<<dim3(NTOT / 64, 8), 256, 0, stream>>>(x, mlp_W1, mlp_b1, t, NTOT, 128, 512, 1, nullptr);
  gemm_f32<<<dim3(NTOT / 64, 2), 256, 0, stream>>>(t, mlp_W2, mlp_b2, x, NTOT, 512, 128, 0, x);
}

// Round 3
// 469.549 us; speedup vs baseline: 1.3126x; 1.3126x over previous
//
#include <hip/hip_runtime.h>
#include <math.h>

#define NTOT  16384
#define NNODE 1024

typedef unsigned short u16;
typedef unsigned short u16x8 __attribute__((ext_vector_type(8)));
typedef short s16x8 __attribute__((ext_vector_type(8)));
typedef float f32x4 __attribute__((ext_vector_type(4)));

static __device__ __forceinline__ float b2f(u16 u) {
  return __uint_as_float(((unsigned)u) << 16);
}
static __device__ __forceinline__ u16 f2b(float f) {
  unsigned x = __float_as_uint(f);
  return (u16)((x + 0x7FFFu + ((x >> 16) & 1u)) >> 16);
}

// ---------------- embedding: h = obs @ Wemb + b (K=32, N=128) ----------------
__global__ __launch_bounds__(64) void emb_k(const float* __restrict__ obs,
    const float* __restrict__ W, const float* __restrict__ b,
    float* __restrict__ h, float* __restrict__ hh, u16* __restrict__ h_bf)
{
  int n = blockIdx.x, l = threadIdx.x;
  __shared__ float ob[32];
  if (l < 32) ob[l] = obs[n * 32 + l];
  __syncthreads();
  float a0 = b[l], a1 = b[64 + l];
  #pragma unroll
  for (int k = 0; k < 32; ++k) {
    float o = ob[k];
    a0 = fmaf(o, W[k * 128 + l], a0);
    a1 = fmaf(o, W[k * 128 + 64 + l], a1);
  }
  size_t base = (size_t)n * 128;
  h[base + l] = a0;  h[base + 64 + l] = a1;
  hh[base + l] = a0; hh[base + 64 + l] = a1;
  h_bf[base + l] = f2b(a0); h_bf[base + 64 + l] = f2b(a1);
}

// ---------------- CSR build ----------------
__global__ void hist_k(const int* __restrict__ ei, int E0, int* __restrict__ deg)
{
  int i = blockIdx.x * blockDim.x + threadIdx.x;
  int ET = E0 + NTOT;
  if (i < ET) {
    int d = (i < E0) ? ei[E0 + i] : (i - E0);
    atomicAdd(&deg[d], 1);
  }
}

__global__ __launch_bounds__(256) void scan_k(const int* __restrict__ deg,
    int* __restrict__ off, int* __restrict__ cursor)
{
  __shared__ int part[256];
  int t = threadIdx.x;
  int base = t * 64;
  int sum = 0;
  for (int i = 0; i < 64; ++i) sum += deg[base + i];
  part[t] = sum;
  __syncthreads();
  if (t == 0) {
    int run = 0;
    for (int i = 0; i < 256; ++i) { int v = part[i]; part[i] = run; run += v; }
  }
  __syncthreads();
  int run = part[t];
  for (int i = 0; i < 64; ++i) {
    off[base + i] = run; cursor[base + i] = run;
    run += deg[base + i];
  }
  if (t == 255) off[NTOT] = run;
}

__global__ void scat_k(const int* __restrict__ ei, int E0,
    int* __restrict__ cursor, int* __restrict__ csr_src)
{
  int i = blockIdx.x * blockDim.x + threadIdx.x;
  int ET = E0 + NTOT;
  if (i < ET) {
    int s, d;
    if (i < E0) { s = ei[i]; d = ei[E0 + i]; } else { s = d = i - E0; }
    int pos = atomicAdd(&cursor[d], 1);
    csr_src[pos] = s;
  }
}

// static fully-connected 16-node cluster graphs (self-loops once)
__global__ void hi_k(int* __restrict__ hi_off, int* __restrict__ hi_src)
{
  int t = threadIdx.x;
  hi_off[t] = t * 16;
  if (t == 0) hi_off[256] = 4096;
  for (int i = t; i < 4096; i += 256) {
    int u = i >> 4;
    hi_src[i] = (u & ~15) + (i & 15);
  }
}

// ---------------- weight transpose + bf16 quantize: out[m][n][k] = bf16(W[m][k][n])
__global__ void wq_k(const float* __restrict__ W, u16* __restrict__ out,
                     int K, int N, int total)
{
  int idx = blockIdx.x * 256 + threadIdx.x;
  if (idx >= total) return;
  int kn = K * N;
  int m = idx / kn, r = idx - m * kn;
  int n = r / K, k = r - n * K;
  out[idx] = f2b(W[(size_t)m * kn + (size_t)k * N + n]);
}

// ---------------- bf16 MFMA GEMM: C = A[M,K] @ Bt[N,K]^T + bias ----------------
// tile 128x128, BK=128 staged in LDS (XOR-swizzled 16B granules), 4 waves.
// epilogue: +bias, optional tanh, optional fp32-residual, writes fp32 and/or bf16.
__global__ __launch_bounds__(256) void gemm_bf16(
    const u16* __restrict__ A, const u16* __restrict__ Bt,
    const float* __restrict__ bias,
    float* __restrict__ Cf, u16* __restrict__ Cb,
    const float* __restrict__ res,
    int M, int K, int N, int act)
{
  __shared__ u16 Al[128][128];
  __shared__ u16 Bl[128][128];
  const int tid = threadIdx.x;
  const int bm = blockIdx.x * 128, bn = blockIdx.y * 128;
  const int w = tid >> 6, l = tid & 63;
  const int fr = l & 15;             // frag row (A) / col (B)
  const int kg = l >> 4;             // k-granule within 32-k step (0..3)
  const int sr = tid >> 1;           // staging row 0..127
  const int sh = (tid & 1) << 3;     // staging granule base (0 or 8)

  f32x4 acc[2][8];
  #pragma unroll
  for (int a = 0; a < 2; ++a)
    #pragma unroll
    for (int b = 0; b < 8; ++b)
      acc[a][b] = (f32x4){0.f, 0.f, 0.f, 0.f};

  for (int k0 = 0; k0 < K; k0 += 128) {
    __syncthreads();
    const u16* As = A + (size_t)(bm + sr) * K + k0 + (sh << 3);
    const u16* Bs = Bt + (size_t)(bn + sr) * K + k0 + (sh << 3);
    #pragma unroll
    for (int i = 0; i < 8; ++i) {
      int gs = (sh + i) ^ (sr & 7);
      *(uint4*)&Al[sr][gs << 3] = *(const uint4*)(As + (i << 3));
    }
    #pragma unroll
    for (int i = 0; i < 8; ++i) {
      int gs = (sh + i) ^ (sr & 7);
      *(uint4*)&Bl[sr][gs << 3] = *(const uint4*)(Bs + (i << 3));
    }
    __syncthreads();
    #pragma unroll
    for (int ks = 0; ks < 4; ++ks) {
      const int g = (ks << 2) + kg;
      const int ar0 = w * 32 + fr, ar1 = ar0 + 16;
      s16x8 a0 = *(const s16x8*)&Al[ar0][(g ^ (ar0 & 7)) << 3];
      s16x8 a1 = *(const s16x8*)&Al[ar1][(g ^ (ar1 & 7)) << 3];
      #pragma unroll
      for (int nr = 0; nr < 8; ++nr) {
        const int br = nr * 16 + fr;
        s16x8 bb = *(const s16x8*)&Bl[br][(g ^ (br & 7)) << 3];
        acc[0][nr] = __builtin_amdgcn_mfma_f32_16x16x32_bf16(a0, bb, acc[0][nr], 0, 0, 0);
        acc[1][nr] = __builtin_amdgcn_mfma_f32_16x16x32_bf16(a1, bb, acc[1][nr], 0, 0, 0);
      }
    }
  }

  // epilogue: C/D layout col = l&15, row = (l>>4)*4 + reg
  #pragma unroll
  for (int mr = 0; mr < 2; ++mr) {
    const int row0 = bm + w * 32 + mr * 16 + (kg << 2);
    #pragma unroll
    for (int nr = 0; nr < 8; ++nr) {
      const int col = bn + nr * 16 + fr;
      const float bb = bias[col];
      #pragma unroll
      for (int j = 0; j < 4; ++j) {
        float v = acc[mr][nr][j] + bb;
        if (act) v = tanhf(v);
        size_t o = (size_t)(row0 + j) * N + col;
        if (res) v += res[o];
        if (Cf) Cf[o] = v;
        if (Cb) Cb[o] = f2b(v);
      }
    }
  }
}

// ---------------- fused GATv2: single-pass online softmax aggregate +
// mean-heads + bias + LN (+SiLU) + residual(s). One wave per dst node;
// lane l owns elems l*8..l*8+7 of the 512-wide (4 heads x 128) bf16 features.
__global__ __launch_bounds__(64) void gat_agg(
    const u16* __restrict__ xl, const u16* __restrict__ xr,
    const int* __restrict__ off, const int* __restrict__ srcs,
    const float* __restrict__ att, const float* __restrict__ bias,
    const float* __restrict__ g, const float* __restrict__ beta,
    float* __restrict__ h, u16* __restrict__ h_bf,
    const float* __restrict__ res2, int do_silu, int swz)
{
  int b = blockIdx.x, l = threadIdx.x;
  int dst;
  if (swz) {
    // pin graphs to XCDs: XCD x (= blockIdx%8) serves graphs {2x, 2x+1};
    // per-XCD xl working set = 2 graphs * 1 KB * 1024 = 2 MB (L2-resident)
    int xcd = b & 7, i = b >> 3;
    dst = (((xcd << 1) + (i >> 10)) << 10) | (i & 1023);
  } else dst = b;

  float xrr[8], attr[8];
  {
    u16x8 vx = *(const u16x8*)(xr + (size_t)dst * 512 + l * 8);
    #pragma unroll
    for (int i = 0; i < 8; ++i) xrr[i] = b2f(vx[i]);
    const float4 a0 = *(const float4*)(att + l * 8);
    const float4 a1 = *(const float4*)(att + l * 8 + 4);
    attr[0] = a0.x; attr[1] = a0.y; attr[2] = a0.z; attr[3] = a0.w;
    attr[4] = a1.x; attr[5] = a1.y; attr[6] = a1.z; attr[7] = a1.w;
  }
  int e0 = off[dst], e1 = off[dst + 1];
  float m = -1e30f, z = 0.f;
  float acc[8] = {0.f, 0.f, 0.f, 0.f, 0.f, 0.f, 0.f, 0.f};
  for (int e = e0; e < e1; ++e) {
    u16x8 vv = *(const u16x8*)(xl + (size_t)srcs[e] * 512 + l * 8);
    float xv[8];
    #pragma unroll
    for (int i = 0; i < 8; ++i) xv[i] = b2f(vv[i]);
    float part = 0.f;
    #pragma unroll
    for (int i = 0; i < 8; ++i) {
      float v = xv[i] + xrr[i];
      v = v > 0.f ? v : 0.2f * v;
      part = fmaf(v, attr[i], part);
    }
    part += __shfl_xor(part, 1); part += __shfl_xor(part, 2);
    part += __shfl_xor(part, 4); part += __shfl_xor(part, 8);
    float mn = fmaxf(m, part);
    float s = __expf(m - mn);     // first iter: exp(-inf)=0
    float p = __expf(part - mn);
    z = z * s + p;
    #pragma unroll
    for (int i = 0; i < 8; ++i) acc[i] = fmaf(acc[i], s, p * xv[i]);
    m = mn;
  }
  float inv = 0.25f / z;          // mean over 4 heads folded in
  int d0 = (l & 15) * 8;
  float o[8];
  #pragma unroll
  for (int i = 0; i < 8; ++i) {
    float v = acc[i] * inv;
    v += __shfl_xor(v, 16);       // sum the 4 heads
    v += __shfl_xor(v, 32);
    o[i] = v + bias[d0 + i];
  }
  // LayerNorm over 128 dims (each 16-lane group holds a full copy)
  float ssum = 0.f;
  #pragma unroll
  for (int i = 0; i < 8; ++i) ssum += o[i];
  ssum += __shfl_xor(ssum, 1); ssum += __shfl_xor(ssum, 2);
  ssum += __shfl_xor(ssum, 4); ssum += __shfl_xor(ssum, 8);
  float mu = ssum * (1.f / 128.f);
  float vs = 0.f;
  #pragma unroll
  for (int i = 0; i < 8; ++i) { float d = o[i] - mu; vs += d * d; }
  vs += __shfl_xor(vs, 1); vs += __shfl_xor(vs, 2);
  vs += __shfl_xor(vs, 4); vs += __shfl_xor(vs, 8);
  float rstd = rsqrtf(vs * (1.f / 128.f) + 1e-5f);
  if (l < 16) {
    size_t base = (size_t)dst * 128 + d0;
    float out[8];
    u16x8 hb;
    #pragma unroll
    for (int i = 0; i < 8; ++i) {
      float y = (o[i] - mu) * rstd * g[d0 + i] + beta[d0 + i];
      if (do_silu) y = y / (1.f + __expf(-y));
      float r = h[base + i];
      if (res2) r += res2[base + i];
      out[i] = y + r;
      hb[i] = f2b(out[i]);
    }
    *(float4*)(h + base) = make_float4(out[0], out[1], out[2], out[3]);
    *(float4*)(h + base + 4) = make_float4(out[4], out[5], out[6], out[7]);
    *(u16x8*)(h_bf + base) = hb;
  }
}

// ---------------- pooling assignments: s = softmax(h @ Wp + bp) over 16 ----------------
__global__ __launch_bounds__(256) void pool_k(const float* __restrict__ h,
    const float* __restrict__ W, const float* __restrict__ b, float* __restrict__ s)
{
  __shared__ float hs[16 * 130];
  __shared__ float Ws[128 * 16];
  int t = threadIdx.x;
  int n0 = blockIdx.x * 16;
  #pragma unroll
  for (int i = 0; i < 8; ++i) {
    int idx = t + 256 * i;
    hs[(idx >> 7) * 130 + (idx & 127)] = h[(size_t)n0 * 128 + idx];
    Ws[idx] = W[idx];
  }
  __syncthreads();
  int nl = t >> 4, c = t & 15;
  float acc = b[c];
  for (int k = 0; k < 128; ++k) acc = fmaf(hs[nl * 130 + k], Ws[k * 16 + c], acc);
  float mx = acc;
  mx = fmaxf(mx, __shfl_xor(mx, 1)); mx = fmaxf(mx, __shfl_xor(mx, 2));
  mx = fmaxf(mx, __shfl_xor(mx, 4)); mx = fmaxf(mx, __shfl_xor(mx, 8));
  float p = __expf(acc - mx), sum = p;
  sum += __shfl_xor(sum, 1); sum += __shfl_xor(sum, 2);
  sum += __shfl_xor(sum, 4); sum += __shfl_xor(sum, 8);
  s[(size_t)(n0 + nl) * 16 + c] = p / sum;
}

// ---------------- cluster features ----------------
__global__ __launch_bounds__(128) void hf_k(const float* __restrict__ s,
    const float* __restrict__ h, float* __restrict__ Hf, float* __restrict__ HfRes,
    u16* __restrict__ Hf_bf)
{
  int b = blockIdx.x >> 4, c = blockIdx.x & 15, d = threadIdx.x;
  float acc = 0.f, cnt = 0.f;
  for (int n = 0; n < NNODE; ++n) {
    float sv = s[(size_t)(b * NNODE + n) * 16 + c];
    cnt += sv;
    acc = fmaf(sv, h[(size_t)(b * NNODE + n) * 128 + d], acc);
  }
  cnt = fmaxf(cnt, 1e-5f);
  float v = acc / cnt;
  size_t o = (size_t)(b * 16 + c) * 128 + d;
  Hf[o] = v; HfRes[o] = v; Hf_bf[o] = f2b(v);
}

// ---------------- unpool + residual: x = s @ Hf + hh ----------------
__global__ __launch_bounds__(64) void unpool_k(const float* __restrict__ s,
    const float* __restrict__ Hf, const float* __restrict__ hh,
    float* __restrict__ x, u16* __restrict__ x_bf)
{
  int n = blockIdx.x, l = threadIdx.x;
  int b = n >> 10;
  float a0 = 0.f, a1 = 0.f;
  #pragma unroll
  for (int c = 0; c < 16; ++c) {
    float sv = s[(size_t)n * 16 + c];
    const float* hp = Hf + (size_t)((b << 4) + c) * 128;
    a0 = fmaf(sv, hp[l], a0);
    a1 = fmaf(sv, hp[64 + l], a1);
  }
  size_t base = (size_t)n * 128;
  float v0 = a0 + hh[base + l], v1 = a1 + hh[base + 64 + l];
  x[base + l] = v0; x[base + 64 + l] = v1;
  x_bf[base + l] = f2b(v0); x_bf[base + 64 + l] = f2b(v1);
}

extern "C" void kernel_launch(void* const* d_in, const int* in_sizes, int n_in,
                              void* d_out, int out_size, void* d_ws, size_t ws_size,
                              hipStream_t stream) {
  (void)n_in; (void)out_size; (void)ws_size;
  const float* obs    = (const float*)d_in[0];
  const int*   ei     = (const int*)d_in[1];
  const float* emb_W  = (const float*)d_in[3];
  const float* emb_b  = (const float*)d_in[4];
  const float* pool_W = (const float*)d_in[5];
  const float* pool_b = (const float*)d_in[6];
  const float* mlp_W1 = (const float*)d_in[7];
  const float* mlp_b1 = (const float*)d_in[8];
  const float* mlp_W2 = (const float*)d_in[9];
  const float* mlp_b2 = (const float*)d_in[10];
  const float* lWl = (const float*)d_in[11]; const float* lbl = (const float*)d_in[12];
  const float* lWr = (const float*)d_in[13]; const float* lbr = (const float*)d_in[14];
  const float* latt = (const float*)d_in[15]; const float* lbias = (const float*)d_in[16];
  const float* lg = (const float*)d_in[17]; const float* lbeta = (const float*)d_in[18];
  const float* hWl = (const float*)d_in[19]; const float* hbl = (const float*)d_in[20];
  const float* hWr = (const float*)d_in[21]; const float* hbr = (const float*)d_in[22];
  const float* hatt = (const float*)d_in[23]; const float* hbias = (const float*)d_in[24];
  const float* hg = (const float*)d_in[25]; const float* hbeta = (const float*)d_in[26];

  const int E0 = in_sizes[1] / 2;
  const int ET = E0 + NTOT;

  char* p = (char*)d_ws;
  auto alloc = [&](size_t bytes) -> void* {
    void* q = (void*)p;
    p += (bytes + 255) & ~(size_t)255;
    return q;
  };
  float* h      = (float*)alloc((size_t)NTOT * 128 * 4);
  float* hh     = (float*)alloc((size_t)NTOT * 128 * 4);
  u16*   h_bf   = (u16*)alloc((size_t)NTOT * 128 * 2);
  u16*   xl_bf  = (u16*)alloc((size_t)NTOT * 512 * 2);
  u16*   xr_bf  = (u16*)alloc((size_t)NTOT * 512 * 2);
  u16*   x_bf   = (u16*)alloc((size_t)NTOT * 128 * 2);
  float* s      = (float*)alloc((size_t)NTOT * 16 * 4);
  float* Hf     = (float*)alloc(256 * 128 * 4);
  float* HfRes  = (float*)alloc(256 * 128 * 4);
  u16*   Hf_bf  = (u16*)alloc(256 * 128 * 2);
  u16*   hxl    = (u16*)alloc(256 * 512 * 2);
  u16*   hxr    = (u16*)alloc(256 * 512 * 2);
  u16*   lWlT   = (u16*)alloc(2 * 512 * 128 * 2);
  u16*   lWrT   = (u16*)alloc(2 * 512 * 128 * 2);
  u16*   hWlT   = (u16*)alloc(2 * 512 * 128 * 2);
  u16*   hWrT   = (u16*)alloc(2 * 512 * 128 * 2);
  u16*   W1T    = (u16*)alloc(512 * 128 * 2);
  u16*   W2T    = (u16*)alloc(128 * 512 * 2);
  int* deg      = (int*)alloc((size_t)NTOT * 4);
  int* off      = (int*)alloc((size_t)(NTOT + 1) * 4);
  int* cursor   = (int*)alloc((size_t)NTOT * 4);
  int* csr      = (int*)alloc((size_t)ET * 4);
  int* hi_off   = (int*)alloc(257 * 4);
  int* hi_src   = (int*)alloc(4096 * 4);
  u16* t_bf     = xl_bf;   // alias: xl_bf is free by MLP time

  // weight quantize+transpose (runs every call; tiny)
  wq_k<<<(2 * 65536 + 255) / 256, 256, 0, stream>>>(lWl, lWlT, 128, 512, 2 * 65536);
  wq_k<<<(2 * 65536 + 255) / 256, 256, 0, stream>>>(lWr, lWrT, 128, 512, 2 * 65536);
  wq_k<<<(2 * 65536 + 255) / 256, 256, 0, stream>>>(hWl, hWlT, 128, 512, 2 * 65536);
  wq_k<<<(2 * 65536 + 255) / 256, 256, 0, stream>>>(hWr, hWrT, 128, 512, 2 * 65536);
  wq_k<<<(65536 + 255) / 256, 256, 0, stream>>>(mlp_W1, W1T, 128, 512, 65536);
  wq_k<<<(65536 + 255) / 256, 256, 0, stream>>>(mlp_W2, W2T, 512, 128, 65536);

  hipMemsetAsync(deg, 0, (size_t)NTOT * 4, stream);
  emb_k<<<NTOT, 64, 0, stream>>>(obs, emb_W, emb_b, h, hh, h_bf);
  hist_k<<<(ET + 255) / 256, 256, 0, stream>>>(ei, E0, deg);
  scan_k<<<1, 256, 0, stream>>>(deg, off, cursor);
  scat_k<<<(ET + 255) / 256, 256, 0, stream>>>(ei, E0, cursor, csr);
  hi_k<<<1, 256, 0, stream>>>(hi_off, hi_src);

  // low-level GAT stack (in-place on h; stack residual == hh)
  for (int j = 0; j < 2; ++j) {
    gemm_bf16<<<dim3(NTOT / 128, 4), 256, 0, stream>>>(h_bf, lWlT + j * 65536,
        lbl + j * 512, nullptr, xl_bf, nullptr, NTOT, 128, 512, 0);
    gemm_bf16<<<dim3(NTOT / 128, 4), 256, 0, stream>>>(h_bf, lWrT + j * 65536,
        lbr + j * 512, nullptr, xr_bf, nullptr, NTOT, 128, 512, 0);
    gat_agg<<<NTOT, 64, 0, stream>>>(xl_bf, xr_bf, off, csr, latt + j * 512,
        lbias + j * 128, lg + j * 128, lbeta + j * 128, h, h_bf,
        j == 1 ? hh : nullptr, j == 0 ? 1 : 0, 1);
  }

  pool_k<<<NTOT / 16, 256, 0, stream>>>(h, pool_W, pool_b, s);
  hf_k<<<256, 128, 0, stream>>>(s, h, Hf, HfRes, Hf_bf);

  // high-level GAT stack on 256 cluster nodes (in-place on Hf)
  for (int j = 0; j < 2; ++j) {
    gemm_bf16<<<dim3(2, 4), 256, 0, stream>>>(Hf_bf, hWlT + j * 65536,
        hbl + j * 512, nullptr, hxl, nullptr, 256, 128, 512, 0);
    gemm_bf16<<<dim3(2, 4), 256, 0, stream>>>(Hf_bf, hWrT + j * 65536,
        hbr + j * 512, nullptr, hxr, nullptr, 256, 128, 512, 0);
    gat_agg<<<256, 64, 0, stream>>>(hxl, hxr, hi_off, hi_src, hatt + j * 512,
        hbias + j * 128, hg + j * 128, hbeta + j * 128, Hf, Hf_bf,
        j == 1 ? HfRes : nullptr, j == 0 ? 1 : 0, 0);
  }

  float* x = (float*)d_out;
  unpool_k<<<NTOT, 64, 0, stream>>>(s, Hf, hh, x, x_bf);
  gemm_bf16<<<dim3(NTOT / 128, 4), 256, 0, stream>>>(x_bf, W1T, mlp_b1,
      nullptr, t_bf, nullptr, NTOT, 128, 512, 1);
  gemm_bf16<<<dim3(NTOT / 128, 1), 256, 0, stream>>>(t_bf, W2T, mlp_b2,
      x, nullptr, x, NTOT, 512, 128, 0);
}

// Round 4
// 421.139 us; speedup vs baseline: 1.4635x; 1.1150x over previous
//
#include <hip/hip_runtime.h>
#include <math.h>

#define NTOT  16384
#define NNODE 1024

typedef unsigned short u16;
typedef unsigned short u16x8 __attribute__((ext_vector_type(8)));
typedef short s16x8 __attribute__((ext_vector_type(8)));
typedef float f32x4 __attribute__((ext_vector_type(4)));

static __device__ __forceinline__ float b2f(u16 u) {
  return __uint_as_float(((unsigned)u) << 16);
}
static __device__ __forceinline__ u16 f2b(float f) {
  unsigned x = __float_as_uint(f);
  return (u16)((x + 0x7FFFu + ((x >> 16) & 1u)) >> 16);
}

// ---------------- embedding: h = obs @ Wemb + b (K=32, N=128) ----------------
__global__ __launch_bounds__(64) void emb_k(const float* __restrict__ obs,
    const float* __restrict__ W, const float* __restrict__ b,
    float* __restrict__ h, float* __restrict__ hh, u16* __restrict__ h_bf)
{
  int n = blockIdx.x, l = threadIdx.x;
  __shared__ float ob[32];
  if (l < 32) ob[l] = obs[n * 32 + l];
  __syncthreads();
  float a0 = b[l], a1 = b[64 + l];
  #pragma unroll
  for (int k = 0; k < 32; ++k) {
    float o = ob[k];
    a0 = fmaf(o, W[k * 128 + l], a0);
    a1 = fmaf(o, W[k * 128 + 64 + l], a1);
  }
  size_t base = (size_t)n * 128;
  h[base + l] = a0;  h[base + 64 + l] = a1;
  hh[base + l] = a0; hh[base + 64 + l] = a1;
  h_bf[base + l] = f2b(a0); h_bf[base + 64 + l] = f2b(a1);
}

// ---------------- CSR build ----------------
__global__ void hist_k(const int* __restrict__ ei, int E0, int* __restrict__ deg)
{
  int i = blockIdx.x * blockDim.x + threadIdx.x;
  int ET = E0 + NTOT;
  if (i < ET) {
    int d = (i < E0) ? ei[E0 + i] : (i - E0);
    atomicAdd(&deg[d], 1);
  }
}

__global__ __launch_bounds__(256) void scan_k(const int* __restrict__ deg,
    int* __restrict__ off, int* __restrict__ cursor)
{
  __shared__ int part[256];
  int t = threadIdx.x;
  int base = t * 64;
  int sum = 0;
  for (int i = 0; i < 64; ++i) sum += deg[base + i];
  part[t] = sum;
  __syncthreads();
  if (t == 0) {
    int run = 0;
    for (int i = 0; i < 256; ++i) { int v = part[i]; part[i] = run; run += v; }
  }
  __syncthreads();
  int run = part[t];
  for (int i = 0; i < 64; ++i) {
    off[base + i] = run; cursor[base + i] = run;
    run += deg[base + i];
  }
  if (t == 255) off[NTOT] = run;
}

__global__ void scat_k(const int* __restrict__ ei, int E0,
    int* __restrict__ cursor, int* __restrict__ csr_src)
{
  int i = blockIdx.x * blockDim.x + threadIdx.x;
  int ET = E0 + NTOT;
  if (i < ET) {
    int s, d;
    if (i < E0) { s = ei[i]; d = ei[E0 + i]; } else { s = d = i - E0; }
    int pos = atomicAdd(&cursor[d], 1);
    csr_src[pos] = s;
  }
}

// static fully-connected 16-node cluster graphs (self-loops once)
__global__ void hi_k(int* __restrict__ hi_off, int* __restrict__ hi_src)
{
  int t = threadIdx.x;
  hi_off[t] = t * 16;
  if (t == 0) hi_off[256] = 4096;
  for (int i = t; i < 4096; i += 256) {
    int u = i >> 4;
    hi_src[i] = (u & ~15) + (i & 15);
  }
}

// ---------------- weight transpose + bf16 quantize: out[m][n][k] = bf16(W[m][k][n])
__global__ void wq_k(const float* __restrict__ W, u16* __restrict__ out,
                     int K, int N, int total)
{
  int idx = blockIdx.x * 256 + threadIdx.x;
  if (idx >= total) return;
  int kn = K * N;
  int m = idx / kn, r = idx - m * kn;
  int n = r / K, k = r - n * K;
  out[idx] = f2b(W[(size_t)m * kn + (size_t)k * N + n]);
}

// ---------------- bf16 MFMA GEMM: C = A[M,K] @ Bt[N,K]^T + bias ----------------
__global__ __launch_bounds__(256) void gemm_bf16(
    const u16* __restrict__ A, const u16* __restrict__ Bt,
    const float* __restrict__ bias,
    float* __restrict__ Cf, u16* __restrict__ Cb,
    const float* __restrict__ res,
    int M, int K, int N, int act)
{
  __shared__ u16 Al[128][128];
  __shared__ u16 Bl[128][128];
  const int tid = threadIdx.x;
  const int bm = blockIdx.x * 128, bn = blockIdx.y * 128;
  const int w = tid >> 6, l = tid & 63;
  const int fr = l & 15;
  const int kg = l >> 4;
  const int sr = tid >> 1;
  const int sh = (tid & 1) << 3;

  f32x4 acc[2][8];
  #pragma unroll
  for (int a = 0; a < 2; ++a)
    #pragma unroll
    for (int b = 0; b < 8; ++b)
      acc[a][b] = (f32x4){0.f, 0.f, 0.f, 0.f};

  for (int k0 = 0; k0 < K; k0 += 128) {
    __syncthreads();
    const u16* As = A + (size_t)(bm + sr) * K + k0 + (sh << 3);
    const u16* Bs = Bt + (size_t)(bn + sr) * K + k0 + (sh << 3);
    #pragma unroll
    for (int i = 0; i < 8; ++i) {
      int gs = (sh + i) ^ (sr & 7);
      *(uint4*)&Al[sr][gs << 3] = *(const uint4*)(As + (i << 3));
    }
    #pragma unroll
    for (int i = 0; i < 8; ++i) {
      int gs = (sh + i) ^ (sr & 7);
      *(uint4*)&Bl[sr][gs << 3] = *(const uint4*)(Bs + (i << 3));
    }
    __syncthreads();
    #pragma unroll
    for (int ks = 0; ks < 4; ++ks) {
      const int g = (ks << 2) + kg;
      const int ar0 = w * 32 + fr, ar1 = ar0 + 16;
      s16x8 a0 = *(const s16x8*)&Al[ar0][(g ^ (ar0 & 7)) << 3];
      s16x8 a1 = *(const s16x8*)&Al[ar1][(g ^ (ar1 & 7)) << 3];
      #pragma unroll
      for (int nr = 0; nr < 8; ++nr) {
        const int br = nr * 16 + fr;
        s16x8 bb = *(const s16x8*)&Bl[br][(g ^ (br & 7)) << 3];
        acc[0][nr] = __builtin_amdgcn_mfma_f32_16x16x32_bf16(a0, bb, acc[0][nr], 0, 0, 0);
        acc[1][nr] = __builtin_amdgcn_mfma_f32_16x16x32_bf16(a1, bb, acc[1][nr], 0, 0, 0);
      }
    }
  }

  #pragma unroll
  for (int mr = 0; mr < 2; ++mr) {
    const int row0 = bm + w * 32 + mr * 16 + (kg << 2);
    #pragma unroll
    for (int nr = 0; nr < 8; ++nr) {
      const int col = bn + nr * 16 + fr;
      const float bb = bias[col];
      #pragma unroll
      for (int j = 0; j < 4; ++j) {
        float v = acc[mr][nr][j] + bb;
        if (act) v = tanhf(v);
        size_t o = (size_t)(row0 + j) * N + col;
        if (res) v += res[o];
        if (Cf) Cf[o] = v;
        if (Cb) Cb[o] = f2b(v);
      }
    }
  }
}

// ---------------- fused GATv2: single-pass online softmax, prefetched gathers
__global__ __launch_bounds__(64) void gat_agg(
    const u16* __restrict__ xl, const u16* __restrict__ xr,
    const int* __restrict__ off, const int* __restrict__ srcs,
    const float* __restrict__ att, const float* __restrict__ bias,
    const float* __restrict__ g, const float* __restrict__ beta,
    float* __restrict__ h, u16* __restrict__ h_bf,
    const float* __restrict__ res2, int do_silu, int swz)
{
  int b = blockIdx.x, l = threadIdx.x;
  int dst;
  if (swz) {
    // pin graphs to XCDs: XCD x (= blockIdx%8) serves graphs {2x, 2x+1};
    // per-XCD xl working set = 2 MB (L2-resident)
    int xcd = b & 7, i = b >> 3;
    dst = (((xcd << 1) + (i >> 10)) << 10) | (i & 1023);
  } else dst = b;

  float xrr[8], attr[8];
  {
    u16x8 vx = *(const u16x8*)(xr + (size_t)dst * 512 + l * 8);
    #pragma unroll
    for (int i = 0; i < 8; ++i) xrr[i] = b2f(vx[i]);
    const float4 a0 = *(const float4*)(att + l * 8);
    const float4 a1 = *(const float4*)(att + l * 8 + 4);
    attr[0] = a0.x; attr[1] = a0.y; attr[2] = a0.z; attr[3] = a0.w;
    attr[4] = a1.x; attr[5] = a1.y; attr[6] = a1.z; attr[7] = a1.w;
  }
  int e0 = off[dst], e1 = off[dst + 1];
  float m = -1e30f, z = 0.f;
  float acc[8] = {0.f, 0.f, 0.f, 0.f, 0.f, 0.f, 0.f, 0.f};
  // software pipeline: src index 2 ahead, gathered row 1 ahead
  int sB = (e0 + 1 < e1) ? srcs[e0 + 1] : 0;
  u16x8 vcur = *(const u16x8*)(xl + (size_t)srcs[e0] * 512 + l * 8);
  for (int e = e0; e < e1; ++e) {
    u16x8 vv = vcur;
    if (e + 1 < e1) {
      vcur = *(const u16x8*)(xl + (size_t)sB * 512 + l * 8);
      if (e + 2 < e1) sB = srcs[e + 2];
    }
    float xv[8];
    #pragma unroll
    for (int i = 0; i < 8; ++i) xv[i] = b2f(vv[i]);
    float part = 0.f;
    #pragma unroll
    for (int i = 0; i < 8; ++i) {
      float v = xv[i] + xrr[i];
      v = v > 0.f ? v : 0.2f * v;
      part = fmaf(v, attr[i], part);
    }
    part += __shfl_xor(part, 1); part += __shfl_xor(part, 2);
    part += __shfl_xor(part, 4); part += __shfl_xor(part, 8);
    float mn = fmaxf(m, part);
    float sc = __expf(m - mn);    // first iter: exp(-inf)=0
    float p = __expf(part - mn);
    z = z * sc + p;
    #pragma unroll
    for (int i = 0; i < 8; ++i) acc[i] = fmaf(acc[i], sc, p * xv[i]);
    m = mn;
  }
  float inv = 0.25f / z;          // mean over 4 heads folded in
  int d0 = (l & 15) * 8;
  float o[8];
  #pragma unroll
  for (int i = 0; i < 8; ++i) {
    float v = acc[i] * inv;
    v += __shfl_xor(v, 16);       // sum the 4 heads
    v += __shfl_xor(v, 32);
    o[i] = v + bias[d0 + i];
  }
  float ssum = 0.f;
  #pragma unroll
  for (int i = 0; i < 8; ++i) ssum += o[i];
  ssum += __shfl_xor(ssum, 1); ssum += __shfl_xor(ssum, 2);
  ssum += __shfl_xor(ssum, 4); ssum += __shfl_xor(ssum, 8);
  float mu = ssum * (1.f / 128.f);
  float vs = 0.f;
  #pragma unroll
  for (int i = 0; i < 8; ++i) { float d = o[i] - mu; vs += d * d; }
  vs += __shfl_xor(vs, 1); vs += __shfl_xor(vs, 2);
  vs += __shfl_xor(vs, 4); vs += __shfl_xor(vs, 8);
  float rstd = rsqrtf(vs * (1.f / 128.f) + 1e-5f);
  if (l < 16) {
    size_t base = (size_t)dst * 128 + d0;
    float out[8];
    u16x8 hb;
    #pragma unroll
    for (int i = 0; i < 8; ++i) {
      float y = (o[i] - mu) * rstd * g[d0 + i] + beta[d0 + i];
      if (do_silu) y = y / (1.f + __expf(-y));
      float r = h[base + i];
      if (res2) r += res2[base + i];
      out[i] = y + r;
      hb[i] = f2b(out[i]);
    }
    *(float4*)(h + base) = make_float4(out[0], out[1], out[2], out[3]);
    *(float4*)(h + base + 4) = make_float4(out[4], out[5], out[6], out[7]);
    *(u16x8*)(h_bf + base) = hb;
  }
}

// ---------------- pooling assignments: s = softmax(h @ Wp + bp) over 16 ----------------
__global__ __launch_bounds__(256) void pool_k(const float* __restrict__ h,
    const float* __restrict__ W, const float* __restrict__ b, float* __restrict__ s)
{
  __shared__ float hs[16 * 130];
  __shared__ float Ws[128 * 16];
  int t = threadIdx.x;
  int n0 = blockIdx.x * 16;
  #pragma unroll
  for (int i = 0; i < 8; ++i) {
    int idx = t + 256 * i;
    hs[(idx >> 7) * 130 + (idx & 127)] = h[(size_t)n0 * 128 + idx];
    Ws[idx] = W[idx];
  }
  __syncthreads();
  int nl = t >> 4, c = t & 15;
  float acc = b[c];
  for (int k = 0; k < 128; ++k) acc = fmaf(hs[nl * 130 + k], Ws[k * 16 + c], acc);
  float mx = acc;
  mx = fmaxf(mx, __shfl_xor(mx, 1)); mx = fmaxf(mx, __shfl_xor(mx, 2));
  mx = fmaxf(mx, __shfl_xor(mx, 4)); mx = fmaxf(mx, __shfl_xor(mx, 8));
  float p = __expf(acc - mx), sum = p;
  sum += __shfl_xor(sum, 1); sum += __shfl_xor(sum, 2);
  sum += __shfl_xor(sum, 4); sum += __shfl_xor(sum, 8);
  s[(size_t)(n0 + nl) * 16 + c] = p / sum;
}

// ---------------- cluster features, stage 1: per-(graph, 32-node-chunk) partials
#define HF_CHUNK 32
#define HF_NCH   32
__global__ __launch_bounds__(256) void hfp_k(const float* __restrict__ s,
    const float* __restrict__ h, float* __restrict__ part, float* __restrict__ cpart)
{
  __shared__ float ss[HF_CHUNK][16];
  __shared__ float hs[HF_CHUNK][128];
  int b = blockIdx.x >> 5, chunk = blockIdx.x & 31;
  int n0 = b * NNODE + chunk * HF_CHUNK;
  int t = threadIdx.x;
  // stage s-slice: 32x16 = 512 floats (128 float4, threads 0..127)
  if (t < 128) {
    float4 v = *(const float4*)(s + (size_t)(n0 + (t >> 2)) * 16 + (t & 3) * 4);
    *(float4*)&ss[t >> 2][(t & 3) * 4] = v;
  }
  // stage h-slice: 32x128 = 4096 floats (1024 float4, 4 per thread)
  #pragma unroll
  for (int i = 0; i < 4; ++i) {
    int idx = t + 256 * i;          // float4 index 0..1023
    int row = idx >> 5, c4 = (idx & 31) * 4;
    *(float4*)&hs[row][c4] = *(const float4*)(h + (size_t)(n0 + row) * 128 + c4);
  }
  __syncthreads();
  int d = t & 127, cg = (t >> 7) * 8;
  float acc[8] = {};
  for (int n = 0; n < HF_CHUNK; ++n) {
    float hv = hs[n][d];
    #pragma unroll
    for (int i = 0; i < 8; ++i) acc[i] = fmaf(ss[n][cg + i], hv, acc[i]);
  }
  float* po = part + (size_t)chunk * 32768 + (size_t)(b * 16 + cg) * 128 + d;
  #pragma unroll
  for (int i = 0; i < 8; ++i) po[i * 128] = acc[i];
  if (t < 16) {
    float c = 0.f;
    #pragma unroll
    for (int n = 0; n < HF_CHUNK; ++n) c += ss[n][t];
    cpart[chunk * 256 + b * 16 + t] = c;
  }
}

// ---------------- cluster features, stage 2: reduce chunks + normalize
__global__ __launch_bounds__(256) void hfr_k(const float* __restrict__ part,
    const float* __restrict__ cpart, float* __restrict__ Hf,
    float* __restrict__ HfRes, u16* __restrict__ Hf_bf)
{
  int o = blockIdx.x * 256 + threadIdx.x;   // (b*16+c)*128 + d, 0..32767
  int bc = o >> 7;
  float a = 0.f, cnt = 0.f;
  #pragma unroll 8
  for (int ch = 0; ch < HF_NCH; ++ch) {
    a += part[(size_t)ch * 32768 + o];
    cnt += cpart[ch * 256 + bc];
  }
  float v = a / fmaxf(cnt, 1e-5f);
  Hf[o] = v; HfRes[o] = v; Hf_bf[o] = f2b(v);
}

// ---------------- unpool + residual: x = s @ Hf + hh ----------------
__global__ __launch_bounds__(64) void unpool_k(const float* __restrict__ s,
    const float* __restrict__ Hf, const float* __restrict__ hh,
    float* __restrict__ x, u16* __restrict__ x_bf)
{
  int n = blockIdx.x, l = threadIdx.x;
  int b = n >> 10;
  float a0 = 0.f, a1 = 0.f;
  #pragma unroll
  for (int c = 0; c < 16; ++c) {
    float sv = s[(size_t)n * 16 + c];
    const float* hp = Hf + (size_t)((b << 4) + c) * 128;
    a0 = fmaf(sv, hp[l], a0);
    a1 = fmaf(sv, hp[64 + l], a1);
  }
  size_t base = (size_t)n * 128;
  float v0 = a0 + hh[base + l], v1 = a1 + hh[base + 64 + l];
  x[base + l] = v0; x[base + 64 + l] = v1;
  x_bf[base + l] = f2b(v0); x_bf[base + 64 + l] = f2b(v1);
}

extern "C" void kernel_launch(void* const* d_in, const int* in_sizes, int n_in,
                              void* d_out, int out_size, void* d_ws, size_t ws_size,
                              hipStream_t stream) {
  (void)n_in; (void)out_size; (void)ws_size;
  const float* obs    = (const float*)d_in[0];
  const int*   ei     = (const int*)d_in[1];
  const float* emb_W  = (const float*)d_in[3];
  const float* emb_b  = (const float*)d_in[4];
  const float* pool_W = (const float*)d_in[5];
  const float* pool_b = (const float*)d_in[6];
  const float* mlp_W1 = (const float*)d_in[7];
  const float* mlp_b1 = (const float*)d_in[8];
  const float* mlp_W2 = (const float*)d_in[9];
  const float* mlp_b2 = (const float*)d_in[10];
  const float* lWl = (const float*)d_in[11]; const float* lbl = (const float*)d_in[12];
  const float* lWr = (const float*)d_in[13]; const float* lbr = (const float*)d_in[14];
  const float* latt = (const float*)d_in[15]; const float* lbias = (const float*)d_in[16];
  const float* lg = (const float*)d_in[17]; const float* lbeta = (const float*)d_in[18];
  const float* hWl = (const float*)d_in[19]; const float* hbl = (const float*)d_in[20];
  const float* hWr = (const float*)d_in[21]; const float* hbr = (const float*)d_in[22];
  const float* hatt = (const float*)d_in[23]; const float* hbias = (const float*)d_in[24];
  const float* hg = (const float*)d_in[25]; const float* hbeta = (const float*)d_in[26];

  const int E0 = in_sizes[1] / 2;
  const int ET = E0 + NTOT;

  char* p = (char*)d_ws;
  auto alloc = [&](size_t bytes) -> void* {
    void* q = (void*)p;
    p += (bytes + 255) & ~(size_t)255;
    return q;
  };
  float* h      = (float*)alloc((size_t)NTOT * 128 * 4);
  float* hh     = (float*)alloc((size_t)NTOT * 128 * 4);
  u16*   h_bf   = (u16*)alloc((size_t)NTOT * 128 * 2);
  u16*   xl_bf  = (u16*)alloc((size_t)NTOT * 512 * 2);
  u16*   xr_bf  = (u16*)alloc((size_t)NTOT * 512 * 2);
  u16*   x_bf   = (u16*)alloc((size_t)NTOT * 128 * 2);
  float* s      = (float*)alloc((size_t)NTOT * 16 * 4);
  float* Hf     = (float*)alloc(256 * 128 * 4);
  float* HfRes  = (float*)alloc(256 * 128 * 4);
  u16*   Hf_bf  = (u16*)alloc(256 * 128 * 2);
  u16*   hxl    = (u16*)alloc(256 * 512 * 2);
  u16*   hxr    = (u16*)alloc(256 * 512 * 2);
  float* hfPart = (float*)alloc((size_t)HF_NCH * 32768 * 4);
  float* hfCnt  = (float*)alloc((size_t)HF_NCH * 256 * 4);
  u16*   lWlT   = (u16*)alloc(2 * 512 * 128 * 2);
  u16*   lWrT   = (u16*)alloc(2 * 512 * 128 * 2);
  u16*   hWlT   = (u16*)alloc(2 * 512 * 128 * 2);
  u16*   hWrT   = (u16*)alloc(2 * 512 * 128 * 2);
  u16*   W1T    = (u16*)alloc(512 * 128 * 2);
  u16*   W2T    = (u16*)alloc(128 * 512 * 2);
  int* deg      = (int*)alloc((size_t)NTOT * 4);
  int* off      = (int*)alloc((size_t)(NTOT + 1) * 4);
  int* cursor   = (int*)alloc((size_t)NTOT * 4);
  int* csr      = (int*)alloc((size_t)ET * 4);
  int* hi_off   = (int*)alloc(257 * 4);
  int* hi_src   = (int*)alloc(4096 * 4);
  u16* t_bf     = xl_bf;   // alias: xl_bf is free by MLP time

  // weight quantize+transpose (runs every call; tiny)
  wq_k<<<(2 * 65536 + 255) / 256, 256, 0, stream>>>(lWl, lWlT, 128, 512, 2 * 65536);
  wq_k<<<(2 * 65536 + 255) / 256, 256, 0, stream>>>(lWr, lWrT, 128, 512, 2 * 65536);
  wq_k<<<(2 * 65536 + 255) / 256, 256, 0, stream>>>(hWl, hWlT, 128, 512, 2 * 65536);
  wq_k<<<(2 * 65536 + 255) / 256, 256, 0, stream>>>(hWr, hWrT, 128, 512, 2 * 65536);
  wq_k<<<(65536 + 255) / 256, 256, 0, stream>>>(mlp_W1, W1T, 128, 512, 65536);
  wq_k<<<(65536 + 255) / 256, 256, 0, stream>>>(mlp_W2, W2T, 512, 128, 65536);

  hipMemsetAsync(deg, 0, (size_t)NTOT * 4, stream);
  emb_k<<<NTOT, 64, 0, stream>>>(obs, emb_W, emb_b, h, hh, h_bf);
  hist_k<<<(ET + 255) / 256, 256, 0, stream>>>(ei, E0, deg);
  scan_k<<<1, 256, 0, stream>>>(deg, off, cursor);
  scat_k<<<(ET + 255) / 256, 256, 0, stream>>>(ei, E0, cursor, csr);
  hi_k<<<1, 256, 0, stream>>>(hi_off, hi_src);

  // low-level GAT stack (in-place on h; stack residual == hh)
  for (int j = 0; j < 2; ++j) {
    gemm_bf16<<<dim3(NTOT / 128, 4), 256, 0, stream>>>(h_bf, lWlT + j * 65536,
        lbl + j * 512, nullptr, xl_bf, nullptr, NTOT, 128, 512, 0);
    gemm_bf16<<<dim3(NTOT / 128, 4), 256, 0, stream>>>(h_bf, lWrT + j * 65536,
        lbr + j * 512, nullptr, xr_bf, nullptr, NTOT, 128, 512, 0);
    gat_agg<<<NTOT, 64, 0, stream>>>(xl_bf, xr_bf, off, csr, latt + j * 512,
        lbias + j * 128, lg + j * 128, lbeta + j * 128, h, h_bf,
        j == 1 ? hh : nullptr, j == 0 ? 1 : 0, 1);
  }

  pool_k<<<NTOT / 16, 256, 0, stream>>>(h, pool_W, pool_b, s);
  hfp_k<<<16 * HF_NCH, 256, 0, stream>>>(s, h, hfPart, hfCnt);
  hfr_k<<<128, 256, 0, stream>>>(hfPart, hfCnt, Hf, HfRes, Hf_bf);

  // high-level GAT stack on 256 cluster nodes (in-place on Hf)
  for (int j = 0; j < 2; ++j) {
    gemm_bf16<<<dim3(2, 4), 256, 0, stream>>>(Hf_bf, hWlT + j * 65536,
        hbl + j * 512, nullptr, hxl, nullptr, 256, 128, 512, 0);
    gemm_bf16<<<dim3(2, 4), 256, 0, stream>>>(Hf_bf, hWrT + j * 65536,
        hbr + j * 512, nullptr, hxr, nullptr, 256, 128, 512, 0);
    gat_agg<<<256, 64, 0, stream>>>(hxl, hxr, hi_off, hi_src, hatt + j * 512,
        hbias + j * 128, hg + j * 128, hbeta + j * 128, Hf, Hf_bf,
        j == 1 ? HfRes : nullptr, j == 0 ? 1 : 0, 0);
  }

  float* x = (float*)d_out;
  unpool_k<<<NTOT, 64, 0, stream>>>(s, Hf, hh, x, x_bf);
  gemm_bf16<<<dim3(NTOT / 128, 4), 256, 0, stream>>>(x_bf, W1T, mlp_b1,
      nullptr, t_bf, nullptr, NTOT, 128, 512, 1);
  gemm_bf16<<<dim3(NTOT / 128, 1), 256, 0, stream>>>(t_bf, W2T, mlp_b2,
      x, nullptr, x, NTOT, 512, 128, 0);
}

// Round 5
// 398.582 us; speedup vs baseline: 1.5463x; 1.0566x over previous
//
#include <hip/hip_runtime.h>
#include <math.h>

#define NTOT  16384
#define NNODE 1024

typedef unsigned short u16;
typedef unsigned short u16x8 __attribute__((ext_vector_type(8)));
typedef short s16x8 __attribute__((ext_vector_type(8)));
typedef float f32x4 __attribute__((ext_vector_type(4)));

static __device__ __forceinline__ float b2f(u16 u) {
  return __uint_as_float(((unsigned)u) << 16);
}
static __device__ __forceinline__ u16 f2b(float f) {
  unsigned x = __float_as_uint(f);
  return (u16)((x + 0x7FFFu + ((x >> 16) & 1u)) >> 16);
}

// ---------------- embedding: h = obs @ Wemb + b (K=32, N=128) ----------------
__global__ __launch_bounds__(64) void emb_k(const float* __restrict__ obs,
    const float* __restrict__ W, const float* __restrict__ b,
    float* __restrict__ h, float* __restrict__ hh, u16* __restrict__ h_bf)
{
  int n = blockIdx.x, l = threadIdx.x;
  __shared__ float ob[32];
  if (l < 32) ob[l] = obs[n * 32 + l];
  __syncthreads();
  float a0 = b[l], a1 = b[64 + l];
  #pragma unroll
  for (int k = 0; k < 32; ++k) {
    float o = ob[k];
    a0 = fmaf(o, W[k * 128 + l], a0);
    a1 = fmaf(o, W[k * 128 + 64 + l], a1);
  }
  size_t base = (size_t)n * 128;
  h[base + l] = a0;  h[base + 64 + l] = a1;
  hh[base + l] = a0; hh[base + 64 + l] = a1;
  h_bf[base + l] = f2b(a0); h_bf[base + 64 + l] = f2b(a1);
}

// ---------------- CSR build ----------------
__global__ void hist_k(const int* __restrict__ ei, int E0, int* __restrict__ deg)
{
  int i = blockIdx.x * blockDim.x + threadIdx.x;
  int ET = E0 + NTOT;
  if (i < ET) {
    int d = (i < E0) ? ei[E0 + i] : (i - E0);
    atomicAdd(&deg[d], 1);
  }
}

__global__ __launch_bounds__(256) void scan_k(const int* __restrict__ deg,
    int* __restrict__ off, int* __restrict__ cursor)
{
  __shared__ int part[256];
  int t = threadIdx.x;
  int base = t * 64;
  int sum = 0;
  for (int i = 0; i < 64; ++i) sum += deg[base + i];
  part[t] = sum;
  __syncthreads();
  if (t == 0) {
    int run = 0;
    for (int i = 0; i < 256; ++i) { int v = part[i]; part[i] = run; run += v; }
  }
  __syncthreads();
  int run = part[t];
  for (int i = 0; i < 64; ++i) {
    off[base + i] = run; cursor[base + i] = run;
    run += deg[base + i];
  }
  if (t == 255) off[NTOT] = run;
}

__global__ void scat_k(const int* __restrict__ ei, int E0,
    int* __restrict__ cursor, int* __restrict__ csr_src)
{
  int i = blockIdx.x * blockDim.x + threadIdx.x;
  int ET = E0 + NTOT;
  if (i < ET) {
    int s, d;
    if (i < E0) { s = ei[i]; d = ei[E0 + i]; } else { s = d = i - E0; }
    int pos = atomicAdd(&cursor[d], 1);
    csr_src[pos] = s;
  }
}

// static fully-connected 16-node cluster graphs (self-loops once)
__global__ void hi_k(int* __restrict__ hi_off, int* __restrict__ hi_src)
{
  int t = threadIdx.x;
  hi_off[t] = t * 16;
  if (t == 0) hi_off[256] = 4096;
  for (int i = t; i < 4096; i += 256) {
    int u = i >> 4;
    hi_src[i] = (u & ~15) + (i & 15);
  }
}

// ---------------- weight transpose + bf16 quantize: out[m][n][k] = bf16(W[m][k][n])
__global__ void wq_k(const float* __restrict__ W, u16* __restrict__ out,
                     int K, int N, int total)
{
  int idx = blockIdx.x * 256 + threadIdx.x;
  if (idx >= total) return;
  int kn = K * N;
  int m = idx / kn, r = idx - m * kn;
  int n = r / K, k = r - n * K;
  out[idx] = f2b(W[(size_t)m * kn + (size_t)k * N + n]);
}

// combined [Wl; Wr] transpose: out layer m = [1024 rows][128 k], rows 0-511 Wl, 512-1023 Wr
__global__ void wq2_k(const float* __restrict__ Wl, const float* __restrict__ Wr,
                      u16* __restrict__ out, int total)
{
  int idx = blockIdx.x * 256 + threadIdx.x;
  if (idx >= total) return;
  int m = idx >> 17;            // 1024*128
  int r = idx & 131071;
  int n = r >> 7, k = r & 127;
  const float* W = (n < 512) ? Wl : Wr;
  out[idx] = f2b(W[(size_t)m * 65536 + (size_t)k * 512 + (n & 511)]);
}

// ---------------- bf16 MFMA GEMM: C = A[M,K] @ Bt[N,K]^T + bias ----------------
// split epilogue: cols [0,Nsplit) -> Cb0/bias0, [Nsplit,N) -> Cb1/bias1 (row stride = half width)
__global__ __launch_bounds__(256) void gemm_bf16(
    const u16* __restrict__ A, const u16* __restrict__ Bt,
    const float* __restrict__ bias0, const float* __restrict__ bias1,
    float* __restrict__ Cf, u16* __restrict__ Cb0, u16* __restrict__ Cb1,
    const float* __restrict__ res,
    int M, int K, int N, int Nsplit, int act)
{
  __shared__ u16 Al[128][128];
  __shared__ u16 Bl[128][128];
  const int tid = threadIdx.x;
  const int bm = blockIdx.x * 128, bn = blockIdx.y * 128;
  const int w = tid >> 6, l = tid & 63;
  const int fr = l & 15;
  const int kg = l >> 4;
  const int sr = tid >> 1;
  const int sh = (tid & 1) << 3;

  f32x4 acc[2][8];
  #pragma unroll
  for (int a = 0; a < 2; ++a)
    #pragma unroll
    for (int b = 0; b < 8; ++b)
      acc[a][b] = (f32x4){0.f, 0.f, 0.f, 0.f};

  for (int k0 = 0; k0 < K; k0 += 128) {
    __syncthreads();
    const u16* As = A + (size_t)(bm + sr) * K + k0 + (sh << 3);
    const u16* Bs = Bt + (size_t)(bn + sr) * K + k0 + (sh << 3);
    #pragma unroll
    for (int i = 0; i < 8; ++i) {
      int gs = (sh + i) ^ (sr & 7);
      *(uint4*)&Al[sr][gs << 3] = *(const uint4*)(As + (i << 3));
    }
    #pragma unroll
    for (int i = 0; i < 8; ++i) {
      int gs = (sh + i) ^ (sr & 7);
      *(uint4*)&Bl[sr][gs << 3] = *(const uint4*)(Bs + (i << 3));
    }
    __syncthreads();
    #pragma unroll
    for (int ks = 0; ks < 4; ++ks) {
      const int g = (ks << 2) + kg;
      const int ar0 = w * 32 + fr, ar1 = ar0 + 16;
      s16x8 a0 = *(const s16x8*)&Al[ar0][(g ^ (ar0 & 7)) << 3];
      s16x8 a1 = *(const s16x8*)&Al[ar1][(g ^ (ar1 & 7)) << 3];
      #pragma unroll
      for (int nr = 0; nr < 8; ++nr) {
        const int br = nr * 16 + fr;
        s16x8 bb = *(const s16x8*)&Bl[br][(g ^ (br & 7)) << 3];
        acc[0][nr] = __builtin_amdgcn_mfma_f32_16x16x32_bf16(a0, bb, acc[0][nr], 0, 0, 0);
        acc[1][nr] = __builtin_amdgcn_mfma_f32_16x16x32_bf16(a1, bb, acc[1][nr], 0, 0, 0);
      }
    }
  }

  #pragma unroll
  for (int mr = 0; mr < 2; ++mr) {
    const int row0 = bm + w * 32 + mr * 16 + (kg << 2);
    #pragma unroll
    for (int nr = 0; nr < 8; ++nr) {
      const int col = bn + nr * 16 + fr;
      const int half = (col >= Nsplit);
      const int c2 = half ? col - Nsplit : col;
      const int str = half ? (N - Nsplit) : Nsplit;
      const float bb = half ? bias1[c2] : bias0[c2];
      u16* cb = half ? Cb1 : Cb0;
      #pragma unroll
      for (int j = 0; j < 4; ++j) {
        float v = acc[mr][nr][j] + bb;
        if (act) v = tanhf(v);
        size_t o = (size_t)(row0 + j) * str + c2;
        if (res) v += res[o];
        if (Cf) Cf[o] = v;
        if (cb) cb[o] = f2b(v);
      }
    }
  }
}

// ---------------- dual-dst fused GATv2: one wave handles 2 dst nodes ----------------
static __device__ __forceinline__ void edge_step(
    u16x8 vv, bool valid, const float* xrr, const float* attr,
    float& m, float& z, float* acc)
{
  float xv[8];
  #pragma unroll
  for (int i = 0; i < 8; ++i) xv[i] = b2f(vv[i]);
  float part = 0.f;
  #pragma unroll
  for (int i = 0; i < 8; ++i) {
    float v = xv[i] + xrr[i];
    part = fmaf(fmaxf(v, 0.2f * v), attr[i], part);   // leaky_relu(v,0.2)=max(v,0.2v)
  }
  part += __shfl_xor(part, 1); part += __shfl_xor(part, 2);
  part += __shfl_xor(part, 4); part += __shfl_xor(part, 8);
  if (!valid) part = -1e30f;
  float mn = fmaxf(m, part);
  float sc = __expf(m - mn);      // first edge: exp(-inf)=0
  float p  = __expf(part - mn);
  z = z * sc + p;
  #pragma unroll
  for (int i = 0; i < 8; ++i) acc[i] = fmaf(acc[i], sc, p * xv[i]);
  m = mn;
}

__global__ __launch_bounds__(64) void gat_agg2(
    const u16* __restrict__ xl, const u16* __restrict__ xr,
    const int* __restrict__ off, const int* __restrict__ srcs,
    const float* __restrict__ att, const float* __restrict__ bias,
    const float* __restrict__ g, const float* __restrict__ beta,
    float* __restrict__ h, u16* __restrict__ h_bf,
    const float* __restrict__ res2, int do_silu, int swz)
{
  int b = blockIdx.x, l = threadIdx.x;
  int dst0;
  if (swz) {
    // pin graphs to XCDs: XCD x serves graphs {2x,2x+1}; L2 working set 2 MB/XCD
    int xcd = b & 7, i = b >> 3;            // i: pair index within XCD, 0..1023
    dst0 = (((xcd << 1) + (i >> 9)) << 10) | ((i & 511) << 1);
  } else dst0 = b << 1;
  const int dst1 = dst0 + 1;

  float attr[8];
  {
    const float4 a0 = *(const float4*)(att + l * 8);
    const float4 a1 = *(const float4*)(att + l * 8 + 4);
    attr[0] = a0.x; attr[1] = a0.y; attr[2] = a0.z; attr[3] = a0.w;
    attr[4] = a1.x; attr[5] = a1.y; attr[6] = a1.z; attr[7] = a1.w;
  }
  float xrr0[8], xrr1[8];
  {
    u16x8 v0 = *(const u16x8*)(xr + (size_t)dst0 * 512 + l * 8);
    u16x8 v1 = *(const u16x8*)(xr + (size_t)dst1 * 512 + l * 8);
    #pragma unroll
    for (int i = 0; i < 8; ++i) { xrr0[i] = b2f(v0[i]); xrr1[i] = b2f(v1[i]); }
  }
  const int s0 = off[dst0], n0 = off[dst0 + 1] - s0;
  const int s1 = off[dst1], n1 = off[dst1 + 1] - s1;
  const int nmax = n0 > n1 ? n0 : n1;

  // software pipeline: per-dst, src index 2 ahead + gathered row 1 ahead
  int ni0 = (n0 > 1) ? srcs[s0 + 1] : 0;
  int ni1 = (n1 > 1) ? srcs[s1 + 1] : 0;
  u16x8 v0 = *(const u16x8*)(xl + (size_t)srcs[s0] * 512 + l * 8);
  u16x8 v1 = *(const u16x8*)(xl + (size_t)srcs[s1] * 512 + l * 8);

  float m0 = -1e30f, z0 = 0.f, acc0[8] = {};
  float m1 = -1e30f, z1 = 0.f, acc1[8] = {};

  for (int e = 0; e < nmax; ++e) {
    u16x8 c0 = v0, c1 = v1;
    if (e + 1 < nmax) {
      v0 = *(const u16x8*)(xl + (size_t)ni0 * 512 + l * 8);
      v1 = *(const u16x8*)(xl + (size_t)ni1 * 512 + l * 8);
      if (e + 2 < n0) ni0 = srcs[s0 + e + 2];
      if (e + 2 < n1) ni1 = srcs[s1 + e + 2];
    }
    edge_step(c0, e < n0, xrr0, attr, m0, z0, acc0);
    edge_step(c1, e < n1, xrr1, attr, m1, z1, acc1);
  }

  const int d0 = (l & 15) * 8;
  float o0[8], o1[8];
  const float inv0 = 0.25f / z0, inv1 = 0.25f / z1;   // mean over 4 heads folded
  #pragma unroll
  for (int i = 0; i < 8; ++i) {
    float v = acc0[i] * inv0;
    v += __shfl_xor(v, 16); v += __shfl_xor(v, 32);   // sum heads
    o0[i] = v + bias[d0 + i];
    float w2 = acc1[i] * inv1;
    w2 += __shfl_xor(w2, 16); w2 += __shfl_xor(w2, 32);
    o1[i] = w2 + bias[d0 + i];
  }
  // LayerNorm over 128 dims (each 16-lane group holds a full copy)
  float sa = 0.f, sb = 0.f;
  #pragma unroll
  for (int i = 0; i < 8; ++i) { sa += o0[i]; sb += o1[i]; }
  sa += __shfl_xor(sa, 1); sa += __shfl_xor(sa, 2);
  sa += __shfl_xor(sa, 4); sa += __shfl_xor(sa, 8);
  sb += __shfl_xor(sb, 1); sb += __shfl_xor(sb, 2);
  sb += __shfl_xor(sb, 4); sb += __shfl_xor(sb, 8);
  const float mu0 = sa * (1.f / 128.f), mu1 = sb * (1.f / 128.f);
  float va = 0.f, vb = 0.f;
  #pragma unroll
  for (int i = 0; i < 8; ++i) {
    float d = o0[i] - mu0; va += d * d;
    float e = o1[i] - mu1; vb += e * e;
  }
  va += __shfl_xor(va, 1); va += __shfl_xor(va, 2);
  va += __shfl_xor(va, 4); va += __shfl_xor(va, 8);
  vb += __shfl_xor(vb, 1); vb += __shfl_xor(vb, 2);
  vb += __shfl_xor(vb, 4); vb += __shfl_xor(vb, 8);
  const float rstd0 = rsqrtf(va * (1.f / 128.f) + 1e-5f);
  const float rstd1 = rsqrtf(vb * (1.f / 128.f) + 1e-5f);

  const float* oo = (l < 16) ? o0 : o1;
  const float mu = (l < 16) ? mu0 : mu1;
  const float rstd = (l < 16) ? rstd0 : rstd1;
  const int dd = (l < 16) ? dst0 : dst1;
  if (l < 32) {
    size_t base = (size_t)dd * 128 + d0;
    float4 r0 = *(const float4*)(h + base);
    float4 r1 = *(const float4*)(h + base + 4);
    float rr[8] = {r0.x, r0.y, r0.z, r0.w, r1.x, r1.y, r1.z, r1.w};
    if (res2) {
      float4 q0 = *(const float4*)(res2 + base);
      float4 q1 = *(const float4*)(res2 + base + 4);
      rr[0] += q0.x; rr[1] += q0.y; rr[2] += q0.z; rr[3] += q0.w;
      rr[4] += q1.x; rr[5] += q1.y; rr[6] += q1.z; rr[7] += q1.w;
    }
    float out[8];
    u16x8 hb;
    #pragma unroll
    for (int i = 0; i < 8; ++i) {
      float y = (oo[i] - mu) * rstd * g[d0 + i] + beta[d0 + i];
      if (do_silu) y = y / (1.f + __expf(-y));
      out[i] = y + rr[i];
      hb[i] = f2b(out[i]);
    }
    *(float4*)(h + base) = make_float4(out[0], out[1], out[2], out[3]);
    *(float4*)(h + base + 4) = make_float4(out[4], out[5], out[6], out[7]);
    *(u16x8*)(h_bf + base) = hb;
  }
}

// ---------------- pooling assignments: s = softmax(h @ Wp + bp) over 16 ----------------
__global__ __launch_bounds__(256) void pool_k(const float* __restrict__ h,
    const float* __restrict__ W, const float* __restrict__ b, float* __restrict__ s)
{
  __shared__ float hs[16 * 130];
  __shared__ float Ws[128 * 16];
  int t = threadIdx.x;
  int n0 = blockIdx.x * 16;
  #pragma unroll
  for (int i = 0; i < 8; ++i) {
    int idx = t + 256 * i;
    hs[(idx >> 7) * 130 + (idx & 127)] = h[(size_t)n0 * 128 + idx];
    Ws[idx] = W[idx];
  }
  __syncthreads();
  int nl = t >> 4, c = t & 15;
  float acc = b[c];
  for (int k = 0; k < 128; ++k) acc = fmaf(hs[nl * 130 + k], Ws[k * 16 + c], acc);
  float mx = acc;
  mx = fmaxf(mx, __shfl_xor(mx, 1)); mx = fmaxf(mx, __shfl_xor(mx, 2));
  mx = fmaxf(mx, __shfl_xor(mx, 4)); mx = fmaxf(mx, __shfl_xor(mx, 8));
  float p = __expf(acc - mx), sum = p;
  sum += __shfl_xor(sum, 1); sum += __shfl_xor(sum, 2);
  sum += __shfl_xor(sum, 4); sum += __shfl_xor(sum, 8);
  s[(size_t)(n0 + nl) * 16 + c] = p / sum;
}

// ---------------- cluster features, stage 1: per-(graph, 32-node-chunk) partials
#define HF_CHUNK 32
#define HF_NCH   32
__global__ __launch_bounds__(256) void hfp_k(const float* __restrict__ s,
    const float* __restrict__ h, float* __restrict__ part, float* __restrict__ cpart)
{
  __shared__ float ss[HF_CHUNK][16];
  __shared__ float hs[HF_CHUNK][128];
  int b = blockIdx.x >> 5, chunk = blockIdx.x & 31;
  int n0 = b * NNODE + chunk * HF_CHUNK;
  int t = threadIdx.x;
  if (t < 128) {
    float4 v = *(const float4*)(s + (size_t)(n0 + (t >> 2)) * 16 + (t & 3) * 4);
    *(float4*)&ss[t >> 2][(t & 3) * 4] = v;
  }
  #pragma unroll
  for (int i = 0; i < 4; ++i) {
    int idx = t + 256 * i;
    int row = idx >> 5, c4 = (idx & 31) * 4;
    *(float4*)&hs[row][c4] = *(const float4*)(h + (size_t)(n0 + row) * 128 + c4);
  }
  __syncthreads();
  int d = t & 127, cg = (t >> 7) * 8;
  float acc[8] = {};
  for (int n = 0; n < HF_CHUNK; ++n) {
    float hv = hs[n][d];
    #pragma unroll
    for (int i = 0; i < 8; ++i) acc[i] = fmaf(ss[n][cg + i], hv, acc[i]);
  }
  float* po = part + (size_t)chunk * 32768 + (size_t)(b * 16 + cg) * 128 + d;
  #pragma unroll
  for (int i = 0; i < 8; ++i) po[i * 128] = acc[i];
  if (t < 16) {
    float c = 0.f;
    #pragma unroll
    for (int n = 0; n < HF_CHUNK; ++n) c += ss[n][t];
    cpart[chunk * 256 + b * 16 + t] = c;
  }
}

// ---------------- cluster features, stage 2: reduce chunks + normalize
__global__ __launch_bounds__(256) void hfr_k(const float* __restrict__ part,
    const float* __restrict__ cpart, float* __restrict__ Hf,
    float* __restrict__ HfRes, u16* __restrict__ Hf_bf)
{
  int o = blockIdx.x * 256 + threadIdx.x;
  int bc = o >> 7;
  float a = 0.f, cnt = 0.f;
  #pragma unroll 8
  for (int ch = 0; ch < HF_NCH; ++ch) {
    a += part[(size_t)ch * 32768 + o];
    cnt += cpart[ch * 256 + bc];
  }
  float v = a / fmaxf(cnt, 1e-5f);
  Hf[o] = v; HfRes[o] = v; Hf_bf[o] = f2b(v);
}

// ---------------- unpool + residual: x = s @ Hf + hh ----------------
__global__ __launch_bounds__(64) void unpool_k(const float* __restrict__ s,
    const float* __restrict__ Hf, const float* __restrict__ hh,
    float* __restrict__ x, u16* __restrict__ x_bf)
{
  int n = blockIdx.x, l = threadIdx.x;
  int b = n >> 10;
  float a0 = 0.f, a1 = 0.f;
  #pragma unroll
  for (int c = 0; c < 16; ++c) {
    float sv = s[(size_t)n * 16 + c];
    const float* hp = Hf + (size_t)((b << 4) + c) * 128;
    a0 = fmaf(sv, hp[l], a0);
    a1 = fmaf(sv, hp[64 + l], a1);
  }
  size_t base = (size_t)n * 128;
  float v0 = a0 + hh[base + l], v1 = a1 + hh[base + 64 + l];
  x[base + l] = v0; x[base + 64 + l] = v1;
  x_bf[base + l] = f2b(v0); x_bf[base + 64 + l] = f2b(v1);
}

extern "C" void kernel_launch(void* const* d_in, const int* in_sizes, int n_in,
                              void* d_out, int out_size, void* d_ws, size_t ws_size,
                              hipStream_t stream) {
  (void)n_in; (void)out_size; (void)ws_size;
  const float* obs    = (const float*)d_in[0];
  const int*   ei     = (const int*)d_in[1];
  const float* emb_W  = (const float*)d_in[3];
  const float* emb_b  = (const float*)d_in[4];
  const float* pool_W = (const float*)d_in[5];
  const float* pool_b = (const float*)d_in[6];
  const float* mlp_W1 = (const float*)d_in[7];
  const float* mlp_b1 = (const float*)d_in[8];
  const float* mlp_W2 = (const float*)d_in[9];
  const float* mlp_b2 = (const float*)d_in[10];
  const float* lWl = (const float*)d_in[11]; const float* lbl = (const float*)d_in[12];
  const float* lWr = (const float*)d_in[13]; const float* lbr = (const float*)d_in[14];
  const float* latt = (const float*)d_in[15]; const float* lbias = (const float*)d_in[16];
  const float* lg = (const float*)d_in[17]; const float* lbeta = (const float*)d_in[18];
  const float* hWl = (const float*)d_in[19]; const float* hbl = (const float*)d_in[20];
  const float* hWr = (const float*)d_in[21]; const float* hbr = (const float*)d_in[22];
  const float* hatt = (const float*)d_in[23]; const float* hbias = (const float*)d_in[24];
  const float* hg = (const float*)d_in[25]; const float* hbeta = (const float*)d_in[26];

  const int E0 = in_sizes[1] / 2;
  const int ET = E0 + NTOT;

  char* p = (char*)d_ws;
  auto alloc = [&](size_t bytes) -> void* {
    void* q = (void*)p;
    p += (bytes + 255) & ~(size_t)255;
    return q;
  };
  float* h      = (float*)alloc((size_t)NTOT * 128 * 4);
  float* hh     = (float*)alloc((size_t)NTOT * 128 * 4);
  u16*   h_bf   = (u16*)alloc((size_t)NTOT * 128 * 2);
  u16*   xl_bf  = (u16*)alloc((size_t)NTOT * 512 * 2);
  u16*   xr_bf  = (u16*)alloc((size_t)NTOT * 512 * 2);
  u16*   x_bf   = (u16*)alloc((size_t)NTOT * 128 * 2);
  float* s      = (float*)alloc((size_t)NTOT * 16 * 4);
  float* Hf     = (float*)alloc(256 * 128 * 4);
  float* HfRes  = (float*)alloc(256 * 128 * 4);
  u16*   Hf_bf  = (u16*)alloc(256 * 128 * 2);
  u16*   hxl    = (u16*)alloc(256 * 512 * 2);
  u16*   hxr    = (u16*)alloc(256 * 512 * 2);
  float* hfPart = (float*)alloc((size_t)HF_NCH * 32768 * 4);
  float* hfCnt  = (float*)alloc((size_t)HF_NCH * 256 * 4);
  u16*   lWT    = (u16*)alloc(2 * 1024 * 128 * 2);
  u16*   hWT    = (u16*)alloc(2 * 1024 * 128 * 2);
  u16*   W1T    = (u16*)alloc(512 * 128 * 2);
  u16*   W2T    = (u16*)alloc(128 * 512 * 2);
  int* deg      = (int*)alloc((size_t)NTOT * 4);
  int* off      = (int*)alloc((size_t)(NTOT + 1) * 4);
  int* cursor   = (int*)alloc((size_t)NTOT * 4);
  int* csr      = (int*)alloc((size_t)ET * 4);
  int* hi_off   = (int*)alloc(257 * 4);
  int* hi_src   = (int*)alloc(4096 * 4);
  u16* t_bf     = xl_bf;   // alias: xl_bf is free by MLP time

  // weight quantize+transpose (runs every call; tiny)
  wq2_k<<<(2 * 131072 + 255) / 256, 256, 0, stream>>>(lWl, lWr, lWT, 2 * 131072);
  wq2_k<<<(2 * 131072 + 255) / 256, 256, 0, stream>>>(hWl, hWr, hWT, 2 * 131072);
  wq_k<<<(65536 + 255) / 256, 256, 0, stream>>>(mlp_W1, W1T, 128, 512, 65536);
  wq_k<<<(65536 + 255) / 256, 256, 0, stream>>>(mlp_W2, W2T, 512, 128, 65536);

  hipMemsetAsync(deg, 0, (size_t)NTOT * 4, stream);
  emb_k<<<NTOT, 64, 0, stream>>>(obs, emb_W, emb_b, h, hh, h_bf);
  hist_k<<<(ET + 255) / 256, 256, 0, stream>>>(ei, E0, deg);
  scan_k<<<1, 256, 0, stream>>>(deg, off, cursor);
  scat_k<<<(ET + 255) / 256, 256, 0, stream>>>(ei, E0, cursor, csr);
  hi_k<<<1, 256, 0, stream>>>(hi_off, hi_src);

  // low-level GAT stack (in-place on h; stack residual == hh)
  for (int j = 0; j < 2; ++j) {
    gemm_bf16<<<dim3(NTOT / 128, 8), 256, 0, stream>>>(h_bf, lWT + j * 131072,
        lbl + j * 512, lbr + j * 512, nullptr, xl_bf, xr_bf, nullptr,
        NTOT, 128, 1024, 512, 0);
    gat_agg2<<<NTOT / 2, 64, 0, stream>>>(xl_bf, xr_bf, off, csr, latt + j * 512,
        lbias + j * 128, lg + j * 128, lbeta + j * 128, h, h_bf,
        j == 1 ? hh : nullptr, j == 0 ? 1 : 0, 1);
  }

  pool_k<<<NTOT / 16, 256, 0, stream>>>(h, pool_W, pool_b, s);
  hfp_k<<<16 * HF_NCH, 256, 0, stream>>>(s, h, hfPart, hfCnt);
  hfr_k<<<128, 256, 0, stream>>>(hfPart, hfCnt, Hf, HfRes, Hf_bf);

  // high-level GAT stack on 256 cluster nodes (in-place on Hf)
  for (int j = 0; j < 2; ++j) {
    gemm_bf16<<<dim3(2, 8), 256, 0, stream>>>(Hf_bf, hWT + j * 131072,
        hbl + j * 512, hbr + j * 512, nullptr, hxl, hxr, nullptr,
        256, 128, 1024, 512, 0);
    gat_agg2<<<128, 64, 0, stream>>>(hxl, hxr, hi_off, hi_src, hatt + j * 512,
        hbias + j * 128, hg + j * 128, hbeta + j * 128, Hf, Hf_bf,
        j == 1 ? HfRes : nullptr, j == 0 ? 1 : 0, 0);
  }

  float* x = (float*)d_out;
  unpool_k<<<NTOT, 64, 0, stream>>>(s, Hf, hh, x, x_bf);
  gemm_bf16<<<dim3(NTOT / 128, 4), 256, 0, stream>>>(x_bf, W1T, mlp_b1, nullptr,
      nullptr, t_bf, nullptr, nullptr, NTOT, 128, 512, 512, 1);
  gemm_bf16<<<dim3(NTOT / 128, 1), 256, 0, stream>>>(t_bf, W2T, mlp_b2, nullptr,
      x, nullptr, nullptr, x, NTOT, 512, 128, 128, 0);
}